// Round 1
// baseline (2804.541 us; speedup 1.0000x reference)
//
#include <hip/hip_runtime.h>
#include <stdint.h>

#define STRIDE 128
#define NVOX (STRIDE * STRIDE * STRIDE)   // 2,097,152 voxels
#define NWORDS (NVOX / 64)                // 32,768 u64 bitmap words
#define SCAN_THREADS 1024
#define WORDS_PER_THREAD (NWORDS / SCAN_THREADS)  // 32

// Order-preserving float32 -> uint32 encoding (monotonic for all non-NaN floats).
__device__ __forceinline__ uint32_t enc_f32(float f) {
  uint32_t u = __float_as_uint(f);
  return (u & 0x80000000u) ? ~u : (u | 0x80000000u);
}
__device__ __forceinline__ float dec_f32(uint32_t e) {
  uint32_t u = (e & 0x80000000u) ? (e & 0x7fffffffu) : ~e;
  return __uint_as_float(u);
}

__device__ __forceinline__ int voxel_lin(const float* __restrict__ pos, int i, float vs) {
  float x = pos[3 * (size_t)i + 0];
  float y = pos[3 * (size_t)i + 1];
  float z = pos[3 * (size_t)i + 2];
  int cx = (int)floorf(x / vs);
  int cy = (int)floorf(y / vs);
  int cz = (int)floorf(z / vs);
  return cx + STRIDE * cy + STRIDE * STRIDE * cz;
}

// A: mark occupied voxels
__global__ void k_bits(const float* __restrict__ pos, const float* __restrict__ vs_p,
                       unsigned long long* __restrict__ bitmap, int n) {
  int i = blockIdx.x * blockDim.x + threadIdx.x;
  if (i >= n) return;
  float vs = vs_p[0];
  int lin = voxel_lin(pos, i, vs);
  atomicOr(&bitmap[lin >> 6], 1ull << (lin & 63));
}

// B: exclusive prefix of popcounts over the 32768 bitmap words (single block)
__global__ void k_scan(const unsigned long long* __restrict__ bitmap,
                       uint32_t* __restrict__ wpfx, uint32_t* __restrict__ Mout) {
  __shared__ uint32_t s[SCAN_THREADS];
  int t = threadIdx.x;
  uint32_t cnts[WORDS_PER_THREAD];
  uint32_t sum = 0;
  #pragma unroll
  for (int j = 0; j < WORDS_PER_THREAD; ++j) {
    cnts[j] = (uint32_t)__popcll(bitmap[t * WORDS_PER_THREAD + j]);
    sum += cnts[j];
  }
  s[t] = sum;
  __syncthreads();
  for (int off = 1; off < SCAN_THREADS; off <<= 1) {
    uint32_t v = (t >= off) ? s[t - off] : 0u;
    __syncthreads();
    s[t] += v;
    __syncthreads();
  }
  uint32_t run = s[t] - sum;  // exclusive offset for this thread's chunk
  #pragma unroll
  for (int j = 0; j < WORDS_PER_THREAD; ++j) {
    wpfx[t * WORDS_PER_THREAD + j] = run;
    run += cnts[j];
  }
  if (t == SCAN_THREADS - 1) Mout[0] = s[SCAN_THREADS - 1];
}

// C: per-point atomic max of encoded features into the output row for its voxel rank
__global__ void k_feat(const float* __restrict__ pos, const float* __restrict__ feat,
                       const float* __restrict__ vs_p,
                       const unsigned long long* __restrict__ bitmap,
                       const uint32_t* __restrict__ wpfx,
                       uint32_t* __restrict__ out_feat_enc, int n) {
  int i = blockIdx.x * blockDim.x + threadIdx.x;
  if (i >= n) return;
  float vs = vs_p[0];
  int lin = voxel_lin(pos, i, vs);
  int w = lin >> 6, b = lin & 63;
  unsigned long long below = (b == 0) ? 0ull : (bitmap[w] & ((1ull << b) - 1ull));
  uint32_t rank = wpfx[w] + (uint32_t)__popcll(below);
  const float4* f4 = (const float4*)(feat + (size_t)i * 32);
  uint32_t* dst = out_feat_enc + (size_t)rank * 32;
  #pragma unroll
  for (int q = 0; q < 8; ++q) {
    float4 v = f4[q];
    atomicMax(&dst[q * 4 + 0], enc_f32(v.x));
    atomicMax(&dst[q * 4 + 1], enc_f32(v.y));
    atomicMax(&dst[q * 4 + 2], enc_f32(v.z));
    atomicMax(&dst[q * 4 + 3], enc_f32(v.w));
  }
}

// D: per bitmap word, emit voxel centers + valid=1 in ascending (sorted) order
__global__ void k_pos(const unsigned long long* __restrict__ bitmap,
                      const uint32_t* __restrict__ wpfx,
                      const float* __restrict__ vs_p,
                      float* __restrict__ out_pos, float* __restrict__ out_valid) {
  int w = blockIdx.x * blockDim.x + threadIdx.x;
  if (w >= NWORDS) return;
  unsigned long long word = bitmap[w];
  if (!word) return;
  float vs = vs_p[0];
  uint32_t rank = wpfx[w];
  int base = w * 64;
  while (word) {
    int b = __ffsll((unsigned long long)word) - 1;
    word &= word - 1;
    int v = base + b;
    int cx = v & (STRIDE - 1);
    int cy = (v >> 7) & (STRIDE - 1);
    int cz = v >> 14;
    out_pos[(size_t)rank * 3 + 0] = ((float)cx + 0.5f) * vs;
    out_pos[(size_t)rank * 3 + 1] = ((float)cy + 0.5f) * vs;
    out_pos[(size_t)rank * 3 + 2] = ((float)cz + 0.5f) * vs;
    out_valid[rank] = 1.0f;
    rank++;
  }
}

// Z: rows >= M -> zero positions and valid
__global__ void k_tail(const uint32_t* __restrict__ Mp, float* __restrict__ out_pos,
                       float* __restrict__ out_valid, int n) {
  int r = blockIdx.x * blockDim.x + threadIdx.x;
  if (r >= n) return;
  uint32_t M = Mp[0];
  if ((uint32_t)r < M) return;
  out_pos[(size_t)r * 3 + 0] = 0.0f;
  out_pos[(size_t)r * 3 + 1] = 0.0f;
  out_pos[(size_t)r * 3 + 2] = 0.0f;
  out_valid[r] = 0.0f;
}

// E: in-place decode of encoded features (rows >= M -> 0), 4 u32 per thread
__global__ void k_decode(const uint32_t* __restrict__ Mp, uint32_t* __restrict__ feat_enc,
                         long long n4) {
  long long i = (long long)blockIdx.x * blockDim.x + threadIdx.x;
  if (i >= n4) return;
  uint32_t M = Mp[0];
  uint32_t row = (uint32_t)(i >> 3);  // 8 uint4 per 32-feature row
  uint4 v = ((const uint4*)feat_enc)[i];
  float4 o;
  if (row < M) {
    o.x = dec_f32(v.x);
    o.y = dec_f32(v.y);
    o.z = dec_f32(v.z);
    o.w = dec_f32(v.w);
  } else {
    o = make_float4(0.0f, 0.0f, 0.0f, 0.0f);
  }
  ((float4*)feat_enc)[i] = o;
}

extern "C" void kernel_launch(void* const* d_in, const int* in_sizes, int n_in,
                              void* d_out, int out_size, void* d_ws, size_t ws_size,
                              hipStream_t stream) {
  const float* pos  = (const float*)d_in[0];
  const float* feat = (const float*)d_in[1];
  const float* vs   = (const float*)d_in[2];
  int n = in_sizes[0] / 3;  // 2,000,000

  float*    out_pos   = (float*)d_out;
  uint32_t* out_feat  = (uint32_t*)(out_pos + (size_t)n * 3);
  float*    out_valid = (float*)((float*)out_feat + (size_t)n * 32);

  unsigned long long* bitmap = (unsigned long long*)d_ws;
  uint32_t* wpfx = (uint32_t*)((char*)d_ws + (size_t)NWORDS * 8);
  uint32_t* Mp   = wpfx + NWORDS;

  hipMemsetAsync(bitmap, 0, (size_t)NWORDS * 8, stream);
  hipMemsetAsync(out_feat, 0, (size_t)n * 32 * sizeof(uint32_t), stream);

  int nb = (n + 255) / 256;
  k_bits<<<nb, 256, 0, stream>>>(pos, vs, bitmap, n);
  k_scan<<<1, SCAN_THREADS, 0, stream>>>(bitmap, wpfx, Mp);
  k_feat<<<nb, 256, 0, stream>>>(pos, feat, vs, bitmap, wpfx, out_feat, n);
  k_pos<<<(NWORDS + 255) / 256, 256, 0, stream>>>(bitmap, wpfx, vs, out_pos, out_valid);
  k_tail<<<nb, 256, 0, stream>>>(Mp, out_pos, out_valid, n);
  long long n4 = (long long)n * 8;  // N*32 u32 / 4-per-thread
  k_decode<<<(int)((n4 + 255) / 256), 256, 0, stream>>>(Mp, out_feat, n4);
}

// Round 2
// 484.077 us; speedup vs baseline: 5.7936x; 5.7936x over previous
//
#include <hip/hip_runtime.h>
#include <stdint.h>
#include <float.h>

#define STRIDE 128
#define NVOX (STRIDE * STRIDE * STRIDE)   // 2,097,152 voxels
#define SCAN_BLOCKS 1024
#define SCAN_TPB 256
#define EPT 8                              // SCAN_BLOCKS*SCAN_TPB*EPT == NVOX

typedef unsigned long long u64;

// pack (cnt, occupied) into u64: low32 = count, high32 = occupancy flag sum
__device__ __forceinline__ u64 pack_co(uint32_t c) {
  return (u64)c | ((u64)(c != 0) << 32);
}

__device__ __forceinline__ int voxel_lin(const float* __restrict__ pos, int i, float vs) {
  float x = pos[3 * (size_t)i + 0];
  float y = pos[3 * (size_t)i + 1];
  float z = pos[3 * (size_t)i + 2];
  int cx = (int)floorf(x / vs);
  int cy = (int)floorf(y / vs);
  int cz = (int)floorf(z / vs);
  return cx + STRIDE * cy + STRIDE * STRIDE * cz;
}

// 1: count points per voxel
__global__ void k_count(const float* __restrict__ pos, const float* __restrict__ vs_p,
                        uint32_t* __restrict__ cnt, int n) {
  int i = blockIdx.x * blockDim.x + threadIdx.x;
  if (i >= n) return;
  int lin = voxel_lin(pos, i, vs_p[0]);
  atomicAdd(&cnt[lin], 1u);
}

// 2a: per-block partial sums of packed (cnt, occ)
__global__ void k_scanA(const uint32_t* __restrict__ cnt, u64* __restrict__ part) {
  __shared__ u64 s[SCAN_TPB];
  int t = threadIdx.x;
  const uint32_t* p = cnt + ((size_t)blockIdx.x * SCAN_TPB + t) * EPT;
  uint4 a = ((const uint4*)p)[0];
  uint4 b = ((const uint4*)p)[1];
  u64 sum = pack_co(a.x) + pack_co(a.y) + pack_co(a.z) + pack_co(a.w) +
            pack_co(b.x) + pack_co(b.y) + pack_co(b.z) + pack_co(b.w);
  s[t] = sum;
  __syncthreads();
  for (int off = SCAN_TPB / 2; off > 0; off >>= 1) {
    if (t < off) s[t] += s[t + off];
    __syncthreads();
  }
  if (t == 0) part[blockIdx.x] = s[0];
}

// 2b: exclusive scan of the 1024 partials (single block); M = total occupied
__global__ void k_scanB(u64* __restrict__ part, uint32_t* __restrict__ Mp) {
  __shared__ u64 s[SCAN_BLOCKS];
  int t = threadIdx.x;
  u64 orig = part[t];
  s[t] = orig;
  __syncthreads();
  for (int off = 1; off < SCAN_BLOCKS; off <<= 1) {
    u64 add = (t >= off) ? s[t - off] : 0ull;
    __syncthreads();
    s[t] += add;
    __syncthreads();
  }
  part[t] = s[t] - orig;  // exclusive
  if (t == SCAN_BLOCKS - 1) Mp[0] = (uint32_t)(s[t] >> 32);
}

// 2c: write exclusive prefixes: pfx (point offsets, in-place over cnt) and occ (voxel rank)
__global__ void k_scanC(uint32_t* __restrict__ cnt, uint32_t* __restrict__ occ,
                        const u64* __restrict__ part) {
  __shared__ u64 s[SCAN_TPB];
  int t = threadIdx.x;
  size_t base = ((size_t)blockIdx.x * SCAN_TPB + t) * EPT;
  uint32_t c[EPT];
  uint4 a = ((const uint4*)(cnt + base))[0];
  uint4 b = ((const uint4*)(cnt + base))[1];
  c[0] = a.x; c[1] = a.y; c[2] = a.z; c[3] = a.w;
  c[4] = b.x; c[5] = b.y; c[6] = b.z; c[7] = b.w;
  u64 sum = 0;
  #pragma unroll
  for (int j = 0; j < EPT; ++j) sum += pack_co(c[j]);
  s[t] = sum;
  __syncthreads();
  for (int off = 1; off < SCAN_TPB; off <<= 1) {
    u64 add = (t >= off) ? s[t - off] : 0ull;
    __syncthreads();
    s[t] += add;
    __syncthreads();
  }
  u64 run = part[blockIdx.x] + (s[t] - sum);  // block-excl + thread-excl
  #pragma unroll
  for (int j = 0; j < EPT; ++j) {
    cnt[base + j] = (uint32_t)run;          // point-offset exclusive prefix
    occ[base + j] = (uint32_t)(run >> 32);  // occupied-voxel rank
    run += pack_co(c[j]);
  }
}

// 3: scatter point indices into per-voxel buckets (pfx becomes inclusive prefix)
__global__ void k_scatter(const float* __restrict__ pos, const float* __restrict__ vs_p,
                          uint32_t* __restrict__ pfx, uint32_t* __restrict__ list, int n) {
  int i = blockIdx.x * blockDim.x + threadIdx.x;
  if (i >= n) return;
  int lin = voxel_lin(pos, i, vs_p[0]);
  uint32_t slot = atomicAdd(&pfx[lin], 1u);
  list[slot] = (uint32_t)i;
}

// 4: per-voxel max-pool gather; 8 threads per voxel (4 features each)
__global__ void k_pool(const float* __restrict__ feat, const float* __restrict__ vs_p,
                       const uint32_t* __restrict__ pfx,   // inclusive after scatter
                       const uint32_t* __restrict__ occ,
                       const uint32_t* __restrict__ list,
                       float* __restrict__ out_pos, float* __restrict__ out_feat,
                       float* __restrict__ out_valid) {
  size_t gid = (size_t)blockIdx.x * blockDim.x + threadIdx.x;  // NVOX*8 exact
  int vox = (int)(gid >> 3);
  int q = (int)(gid & 7);
  uint32_t end = pfx[vox];
  uint32_t start = vox ? pfx[vox - 1] : 0u;
  if (end <= start) return;
  float4 acc = make_float4(-FLT_MAX, -FLT_MAX, -FLT_MAX, -FLT_MAX);
  const float4* f4 = (const float4*)feat;
  for (uint32_t u = start; u < end; ++u) {
    uint32_t p = list[u];
    float4 v = f4[(size_t)p * 8 + q];
    acc.x = fmaxf(acc.x, v.x);
    acc.y = fmaxf(acc.y, v.y);
    acc.z = fmaxf(acc.z, v.z);
    acc.w = fmaxf(acc.w, v.w);
  }
  uint32_t rank = occ[vox];
  ((float4*)out_feat)[(size_t)rank * 8 + q] = acc;
  if (q == 0) {
    float vs = vs_p[0];
    int cx = vox & (STRIDE - 1);
    int cy = (vox >> 7) & (STRIDE - 1);
    int cz = vox >> 14;
    out_pos[(size_t)rank * 3 + 0] = ((float)cx + 0.5f) * vs;
    out_pos[(size_t)rank * 3 + 1] = ((float)cy + 0.5f) * vs;
    out_pos[(size_t)rank * 3 + 2] = ((float)cz + 0.5f) * vs;
    out_valid[rank] = 1.0f;
  }
}

// 5: zero rows >= M (features, positions, valid) — also wipes the out-tail scratch
__global__ void k_tail(const uint32_t* __restrict__ Mp, float* __restrict__ out_pos,
                       float* __restrict__ out_feat, float* __restrict__ out_valid, int n) {
  size_t gid = (size_t)blockIdx.x * blockDim.x + threadIdx.x;  // n*8 exact
  int row = (int)(gid >> 3);
  int q = (int)(gid & 7);
  uint32_t M = Mp[0];
  if ((uint32_t)row < M) return;
  ((float4*)out_feat)[(size_t)row * 8 + q] = make_float4(0.f, 0.f, 0.f, 0.f);
  if (q == 0) {
    out_pos[(size_t)row * 3 + 0] = 0.f;
    out_pos[(size_t)row * 3 + 1] = 0.f;
    out_pos[(size_t)row * 3 + 2] = 0.f;
    out_valid[row] = 0.f;
  }
}

extern "C" void kernel_launch(void* const* d_in, const int* in_sizes, int n_in,
                              void* d_out, int out_size, void* d_ws, size_t ws_size,
                              hipStream_t stream) {
  const float* pos  = (const float*)d_in[0];
  const float* feat = (const float*)d_in[1];
  const float* vs   = (const float*)d_in[2];
  int n = in_sizes[0] / 3;  // 2,000,000

  float*    out_pos   = (float*)d_out;
  uint32_t* out_feat  = (uint32_t*)(out_pos + (size_t)n * 3);
  float*    out_valid = (float*)((float*)out_feat + (size_t)n * 32);

  // Scratch in the TAIL of the feature output region: 3 arrays of NVOX u32 (24 MB).
  // These occupy rows >= (n*32 - 3*NVOX)/32 ~= 1,803,392; M <= 1,000,000, so
  // k_pool (writes rows < M) never touches them, and k_tail zeroes them afterwards.
  uint32_t* pfx  = out_feat + (size_t)n * 32 - 3 * (size_t)NVOX;
  uint32_t* occ  = pfx + NVOX;
  uint32_t* list = occ + NVOX;

  // d_ws: only the 1024 u64 scan partials + M
  u64*      part = (u64*)d_ws;
  uint32_t* Mp   = (uint32_t*)(part + SCAN_BLOCKS);

  hipMemsetAsync(pfx, 0, (size_t)NVOX * sizeof(uint32_t), stream);  // cnt = 0

  int nb = (n + 255) / 256;
  k_count<<<nb, 256, 0, stream>>>(pos, vs, pfx, n);
  k_scanA<<<SCAN_BLOCKS, SCAN_TPB, 0, stream>>>(pfx, part);
  k_scanB<<<1, SCAN_BLOCKS, 0, stream>>>(part, Mp);
  k_scanC<<<SCAN_BLOCKS, SCAN_TPB, 0, stream>>>(pfx, occ, part);
  k_scatter<<<nb, 256, 0, stream>>>(pos, vs, pfx, list, n);
  k_pool<<<(int)(((size_t)NVOX * 8) / 256), 256, 0, stream>>>(
      feat, vs, pfx, occ, list, out_pos, (float*)out_feat, out_valid);
  k_tail<<<(int)(((size_t)n * 8) / 256), 256, 0, stream>>>(
      Mp, out_pos, (float*)out_feat, out_valid, n);
}

// Round 3
// 436.422 us; speedup vs baseline: 6.4262x; 1.1092x over previous
//
#include <hip/hip_runtime.h>
#include <stdint.h>
#include <float.h>

#define STRIDE 128
#define NVOX (STRIDE * STRIDE * STRIDE)   // 2,097,152 voxels
#define SCAN_BLOCKS 1024
#define SCAN_TPB 256
#define EPT 8                              // SCAN_BLOCKS*SCAN_TPB*EPT == NVOX

typedef unsigned long long u64;

// pack (cnt, occupied) into u64: low32 = count, high32 = occupancy flag sum
__device__ __forceinline__ u64 pack_co(uint32_t c) {
  return (u64)c | ((u64)(c != 0) << 32);
}

__device__ __forceinline__ int voxel_lin(const float* __restrict__ pos, int i, float vs) {
  float x = pos[3 * (size_t)i + 0];
  float y = pos[3 * (size_t)i + 1];
  float z = pos[3 * (size_t)i + 2];
  int cx = (int)floorf(x / vs);
  int cy = (int)floorf(y / vs);
  int cz = (int)floorf(z / vs);
  return cx + STRIDE * cy + STRIDE * STRIDE * cz;
}

// 1: count points per voxel + cache lin per point
__global__ void k_prep(const float* __restrict__ pos, const float* __restrict__ vs_p,
                       uint32_t* __restrict__ cnt, int* __restrict__ lin_arr, int n) {
  int i = blockIdx.x * blockDim.x + threadIdx.x;
  if (i >= n) return;
  int lin = voxel_lin(pos, i, vs_p[0]);
  lin_arr[i] = lin;
  atomicAdd(&cnt[lin], 1u);
}

// 2a: per-block partial sums of packed (cnt, occ)
__global__ void k_scanA(const uint32_t* __restrict__ cnt, u64* __restrict__ part) {
  __shared__ u64 s[SCAN_TPB];
  int t = threadIdx.x;
  const uint32_t* p = cnt + ((size_t)blockIdx.x * SCAN_TPB + t) * EPT;
  uint4 a = ((const uint4*)p)[0];
  uint4 b = ((const uint4*)p)[1];
  u64 sum = pack_co(a.x) + pack_co(a.y) + pack_co(a.z) + pack_co(a.w) +
            pack_co(b.x) + pack_co(b.y) + pack_co(b.z) + pack_co(b.w);
  s[t] = sum;
  __syncthreads();
  for (int off = SCAN_TPB / 2; off > 0; off >>= 1) {
    if (t < off) s[t] += s[t + off];
    __syncthreads();
  }
  if (t == 0) part[blockIdx.x] = s[0];
}

// 2b: exclusive scan of the 1024 partials (single block); M = total occupied
__global__ void k_scanB(u64* __restrict__ part, uint32_t* __restrict__ Mp) {
  __shared__ u64 s[SCAN_BLOCKS];
  int t = threadIdx.x;
  u64 orig = part[t];
  s[t] = orig;
  __syncthreads();
  for (int off = 1; off < SCAN_BLOCKS; off <<= 1) {
    u64 add = (t >= off) ? s[t - off] : 0ull;
    __syncthreads();
    s[t] += add;
    __syncthreads();
  }
  part[t] = s[t] - orig;  // exclusive
  if (t == SCAN_BLOCKS - 1) Mp[0] = (uint32_t)(s[t] >> 32);
}

// 2c: write exclusive prefixes: pfx (point offsets, in-place over cnt) and occ (voxel rank)
__global__ void k_scanC(uint32_t* __restrict__ cnt, uint32_t* __restrict__ occ,
                        const u64* __restrict__ part) {
  __shared__ u64 s[SCAN_TPB];
  int t = threadIdx.x;
  size_t base = ((size_t)blockIdx.x * SCAN_TPB + t) * EPT;
  uint32_t c[EPT];
  uint4 a = ((const uint4*)(cnt + base))[0];
  uint4 b = ((const uint4*)(cnt + base))[1];
  c[0] = a.x; c[1] = a.y; c[2] = a.z; c[3] = a.w;
  c[4] = b.x; c[5] = b.y; c[6] = b.z; c[7] = b.w;
  u64 sum = 0;
  #pragma unroll
  for (int j = 0; j < EPT; ++j) sum += pack_co(c[j]);
  s[t] = sum;
  __syncthreads();
  for (int off = 1; off < SCAN_TPB; off <<= 1) {
    u64 add = (t >= off) ? s[t - off] : 0ull;
    __syncthreads();
    s[t] += add;
    __syncthreads();
  }
  u64 run = part[blockIdx.x] + (s[t] - sum);  // block-excl + thread-excl
  #pragma unroll
  for (int j = 0; j < EPT; ++j) {
    cnt[base + j] = (uint32_t)run;          // point-offset exclusive prefix
    occ[base + j] = (uint32_t)(run >> 32);  // occupied-voxel rank
    run += pack_co(c[j]);
  }
}

// 3: scatter point indices into per-voxel buckets (pfx becomes inclusive prefix)
__global__ void k_scatter(const int* __restrict__ lin_arr,
                          uint32_t* __restrict__ pfx, uint32_t* __restrict__ list, int n) {
  int i = blockIdx.x * blockDim.x + threadIdx.x;
  if (i >= n) return;
  int lin = lin_arr[i];
  uint32_t slot = atomicAdd(&pfx[lin], 1u);
  list[slot] = (uint32_t)i;
}

__device__ __forceinline__ float4 max4f4(float4 a, float4 b, float4 c, float4 d) {
  float4 r;
  r.x = fmaxf(fmaxf(a.x, b.x), fmaxf(c.x, d.x));
  r.y = fmaxf(fmaxf(a.y, b.y), fmaxf(c.y, d.y));
  r.z = fmaxf(fmaxf(a.z, b.z), fmaxf(c.z, d.z));
  r.w = fmaxf(fmaxf(a.w, b.w), fmaxf(c.w, d.w));
  return r;
}

// 4: per-voxel max-pool gather; 8 threads per voxel (4 features each).
//    4-wide batched gather (clamped indices; duplicates idempotent under max)
//    so each lane keeps 4 feature loads in flight instead of 1.
__global__ void k_pool(const float* __restrict__ feat, const float* __restrict__ vs_p,
                       const uint32_t* __restrict__ pfx,   // inclusive after scatter
                       const uint32_t* __restrict__ occ,
                       const uint32_t* __restrict__ list,
                       float* __restrict__ out_pos, float* __restrict__ out_feat,
                       float* __restrict__ out_valid) {
  size_t gid = (size_t)blockIdx.x * blockDim.x + threadIdx.x;  // NVOX*8 exact
  int vox = (int)(gid >> 3);
  int q = (int)(gid & 7);
  uint32_t end = pfx[vox];
  uint32_t start = vox ? pfx[vox - 1] : 0u;
  if (end <= start) return;
  uint32_t last = end - 1;
  const float4* f4 = (const float4*)feat;

  uint32_t i1 = min(start + 1u, last), i2 = min(start + 2u, last), i3 = min(start + 3u, last);
  uint32_t p0 = list[start], p1 = list[i1], p2 = list[i2], p3 = list[i3];
  float4 v0 = f4[(size_t)p0 * 8 + q];
  float4 v1 = f4[(size_t)p1 * 8 + q];
  float4 v2 = f4[(size_t)p2 * 8 + q];
  float4 v3 = f4[(size_t)p3 * 8 + q];
  float4 acc = max4f4(v0, v1, v2, v3);

  for (uint32_t u = start + 4; u < end; u += 4) {
    uint32_t j1 = min(u + 1u, last), j2 = min(u + 2u, last), j3 = min(u + 3u, last);
    p0 = list[u]; p1 = list[j1]; p2 = list[j2]; p3 = list[j3];
    v0 = f4[(size_t)p0 * 8 + q];
    v1 = f4[(size_t)p1 * 8 + q];
    v2 = f4[(size_t)p2 * 8 + q];
    v3 = f4[(size_t)p3 * 8 + q];
    acc = max4f4(acc, max4f4(v0, v1, v2, v3), v2, v3);  // fmax idempotent
  }

  uint32_t rank = occ[vox];
  ((float4*)out_feat)[(size_t)rank * 8 + q] = acc;
  if (q == 0) {
    float vs = vs_p[0];
    int cx = vox & (STRIDE - 1);
    int cy = (vox >> 7) & (STRIDE - 1);
    int cz = vox >> 14;
    out_pos[(size_t)rank * 3 + 0] = ((float)cx + 0.5f) * vs;
    out_pos[(size_t)rank * 3 + 1] = ((float)cy + 0.5f) * vs;
    out_pos[(size_t)rank * 3 + 2] = ((float)cz + 0.5f) * vs;
    out_valid[rank] = 1.0f;
  }
}

// 5: zero rows >= M (features, positions, valid) — also wipes the out-tail scratch
__global__ void k_tail(const uint32_t* __restrict__ Mp, float* __restrict__ out_pos,
                       float* __restrict__ out_feat, float* __restrict__ out_valid, int n) {
  size_t gid = (size_t)blockIdx.x * blockDim.x + threadIdx.x;  // n*8 exact
  int row = (int)(gid >> 3);
  int q = (int)(gid & 7);
  uint32_t M = Mp[0];
  if ((uint32_t)row < M) return;
  ((float4*)out_feat)[(size_t)row * 8 + q] = make_float4(0.f, 0.f, 0.f, 0.f);
  if (q == 0) {
    out_pos[(size_t)row * 3 + 0] = 0.f;
    out_pos[(size_t)row * 3 + 1] = 0.f;
    out_pos[(size_t)row * 3 + 2] = 0.f;
    out_valid[row] = 0.f;
  }
}

extern "C" void kernel_launch(void* const* d_in, const int* in_sizes, int n_in,
                              void* d_out, int out_size, void* d_ws, size_t ws_size,
                              hipStream_t stream) {
  const float* pos  = (const float*)d_in[0];
  const float* feat = (const float*)d_in[1];
  const float* vs   = (const float*)d_in[2];
  int n = in_sizes[0] / 3;  // 2,000,000

  float*    out_pos   = (float*)d_out;
  uint32_t* out_feat  = (uint32_t*)(out_pos + (size_t)n * 3);
  float*    out_valid = (float*)((float*)out_feat + (size_t)n * 32);

  // Scratch in the TAIL of the feature output region: 4 arrays of NVOX u32 (32 MB).
  // These occupy rows >= ~1,737,856; M <= 1,000,000, so k_pool (writes rows < M)
  // never touches them, and k_tail zeroes them afterwards.
  uint32_t* pfx  = out_feat + (size_t)n * 32 - 4 * (size_t)NVOX;
  uint32_t* occ  = pfx + NVOX;
  uint32_t* list = occ + NVOX;
  int*      lin  = (int*)(list + NVOX);   // n <= NVOX entries

  // d_ws: only the 1024 u64 scan partials + M
  u64*      part = (u64*)d_ws;
  uint32_t* Mp   = (uint32_t*)(part + SCAN_BLOCKS);

  hipMemsetAsync(pfx, 0, (size_t)NVOX * sizeof(uint32_t), stream);  // cnt = 0

  int nb = (n + 255) / 256;
  k_prep<<<nb, 256, 0, stream>>>(pos, vs, pfx, lin, n);
  k_scanA<<<SCAN_BLOCKS, SCAN_TPB, 0, stream>>>(pfx, part);
  k_scanB<<<1, SCAN_BLOCKS, 0, stream>>>(part, Mp);
  k_scanC<<<SCAN_BLOCKS, SCAN_TPB, 0, stream>>>(pfx, occ, part);
  k_scatter<<<nb, 256, 0, stream>>>(lin, pfx, list, n);
  k_pool<<<(int)(((size_t)NVOX * 8) / 256), 256, 0, stream>>>(
      feat, vs, pfx, occ, list, out_pos, (float*)out_feat, out_valid);
  k_tail<<<(int)(((size_t)n * 8) / 256), 256, 0, stream>>>(
      Mp, out_pos, (float*)out_feat, out_valid, n);
}